// Round 2
// baseline (405.167 us; speedup 1.0000x reference)
//
#include <hip/hip_runtime.h>

#define BIG_Z_F 1000000.0f
#define N_MESH 8

// Native Clang vector type for 16B face-row loads.
typedef float f4 __attribute__((ext_vector_type(4)));

// R11: gather de-thrash. R10's fusion was neutral (+8us); the real cost is
// inside the interp loop. With c4 as the OUTER loop, each thread keeps 12
// live face-row lines (4 px x 3 rows, 1 line each) and revisits each 8x at
// a reuse distance far beyond L1 (32KB/CU shared by ~32 waves) -> every 16B
// gather load is an L1 miss -> ~50M line fills from L2 (~3-6 GB) ~= the
// observed ~190us. Fix: row-OUTER / channel-INNER with a per-pixel 32-float
// accumulator; each 128B face row is consumed by 8 consecutive 16B loads
// while hot (1 miss + 7 hits guaranteed), L2 traffic drops ~8x.
//   - 1 pixel/thread (acc = 8 f4 = 32 VGPR; avoids R8's 48-f4 VGPR trap).
//   - out_map becomes 4B scalar NT stores; lanes cover consecutive pixels
//     -> every store instr is a full 256B coalesced segment.
//   - face-row loads are PLAIN (cached) on purpose: the fix IS the L1 reuse.
//   - Cross-mesh reduction + vv scatter stay fused (R10), now scalar.
//   - All single-use streams stay NT; fmem does not.

// ---------------------------------------------------------------------------
// Tiny init kernel: zero vertex-visibility accumulator (40 KB).
// ---------------------------------------------------------------------------
__global__ __launch_bounds__(256) void zero_vv(
    float* __restrict__ vv, int V)
{
    const int i = blockIdx.x * blockDim.x + threadIdx.x;
    if (i < V) vv[i] = 0.0f;
}

// ---------------------------------------------------------------------------
// Fused kernel: per-(mesh, pixel). Cross-mesh reduction + mask/zb +
// p/d/bc outputs + gather-interp out_map + direct vv scatter.
// ---------------------------------------------------------------------------
__global__ __launch_bounds__(256) void raster_fused(
    const float* __restrict__ zbuf,   // (N, HW) — cached loads, 8x reuse
    const int*   __restrict__ p2f,    // (N, HW)
    const float* __restrict__ bary,   // (N, HW, 3)
    const float* __restrict__ dists,  // (N, HW)
    const float* __restrict__ fmem,   // (F,3,C) — row = 32 fl = one 128B line
    const int*   __restrict__ pfaces, // (F,3)
    const int*   __restrict__ mdp,    // scalar mask_duplicate
    float* __restrict__ out_map,      // (N,C,HW)
    float* __restrict__ maskO,        // (N, HW)
    float* __restrict__ zbO,          // (N, HW)
    float* __restrict__ pO,           // (N, HW)
    float* __restrict__ dO,           // (N, HW)
    float* __restrict__ bcO,          // (N, HW, 3)
    float* __restrict__ vv,           // (V), pre-zeroed by zero_vv
    int HW, int C)
{
    const int pix = blockIdx.x * blockDim.x + threadIdx.x;
    if (pix >= HW) return;
    const int n   = blockIdx.y;
    const int idx = n * HW + pix;
    const int md  = *mdp;

    // ---- cross-mesh reduction (running scalars; no runtime-indexed array)
    int   cnt  = 0;
    float best = __builtin_inff();
    int   bi   = 0;
    float zown = 0.0f;
    #pragma unroll
    for (int nn = 0; nn < N_MESH; ++nn) {
        const float zv = zbuf[nn * HW + pix];   // plain load: L2/L3-resident
        if (nn == n) zown = zv;                 // uniform select (n uniform)
        cnt += (zv > -1.0f) ? 1 : 0;
        const float t = (zv < 0.0f) ? BIG_Z_F : zv;
        if (t < best) { best = t; bi = nn; }    // strict < => first-win tie
    }
    const bool dup = (cnt > 1) && ((md != 0) || (n != bi));

    __builtin_nontemporal_store((zown >= 0.0f) ? 1.0f : 0.0f, &maskO[idx]);
    __builtin_nontemporal_store(dup ? -1.0f : zown, &zbO[idx]);

    // ---- per-pixel p/d/bc outputs (same semantics as R9/R10)
    const int   praw = __builtin_nontemporal_load(&p2f[idx]);
    const float drw  = __builtin_nontemporal_load(&dists[idx]);
    const float br0  = bary[idx * 3 + 0];   // plain: stride-12, L1-shared
    const float br1  = bary[idx * 3 + 1];
    const float br2  = bary[idx * 3 + 2];

    const int  p     = dup ? -1 : praw;
    const bool valid = (p >= 0);
    const int  safe  = valid ? p : 0;

    const float bst0 = dup ? -1.0f : br0;
    const float bst1 = dup ? -1.0f : br1;
    const float bst2 = dup ? -1.0f : br2;
    const float bc0  = valid ? bst0 : 0.0f;
    const float bc1  = valid ? bst1 : 0.0f;
    const float bc2  = valid ? bst2 : 0.0f;

    __builtin_nontemporal_store((float)p, &pO[idx]);
    __builtin_nontemporal_store(dup ? -1.0f : drw, &dO[idx]);
    __builtin_nontemporal_store(bst0, &bcO[idx * 3 + 0]);
    __builtin_nontemporal_store(bst1, &bcO[idx * 3 + 1]);
    __builtin_nontemporal_store(bst2, &bcO[idx * 3 + 2]);

    // ---- direct vertex-visibility scatter (~1/8 lanes active)
    if (valid) {
        const int b = safe * 3;
        vv[pfaces[b + 0]] = 1.0f;
        vv[pfaces[b + 1]] = 1.0f;
        vv[pfaces[b + 2]] = 1.0f;
    }

    // ---- gather + interp: row-outer / channel-inner, per-pixel accumulator.
    // Each face row (128B-aligned line) is consumed hot: 8 consecutive 16B
    // plain loads -> 1 L1 miss + 7 hits. acc association matches the old
    // bc0*a0 + bc1*a1 + bc2*a2 left-to-right fma chain.
    const float* a = fmem + (size_t)safe * 3 * C;
    f4 acc[8];
    #pragma unroll
    for (int c4 = 0; c4 < 8; ++c4) {
        const f4 a0 = *(const f4*)(a + 4 * c4);
        acc[c4] = bc0 * a0;
    }
    #pragma unroll
    for (int c4 = 0; c4 < 8; ++c4) {
        const f4 a1 = *(const f4*)(a + C + 4 * c4);
        acc[c4] += bc1 * a1;
    }
    #pragma unroll
    for (int c4 = 0; c4 < 8; ++c4) {
        const f4 a2 = *(const f4*)(a + 2 * C + 4 * c4);
        acc[c4] += bc2 * a2;
    }

    // Stores: channel-major out (n,C,HW); lanes cover consecutive pix ->
    // each 4B NT store instruction is a full coalesced 256B segment.
    #pragma unroll
    for (int c4 = 0; c4 < 8; ++c4) {
        #pragma unroll
        for (int k = 0; k < 4; ++k) {
            __builtin_nontemporal_store(
                acc[c4][k], &out_map[(size_t)(n * C + c4 * 4 + k) * HW + pix]);
        }
    }
}

extern "C" void kernel_launch(void* const* d_in, const int* in_sizes, int n_in,
                              void* d_out, int out_size, void* d_ws, size_t ws_size,
                              hipStream_t stream) {
    const float* zbuf   = (const float*)d_in[0];
    const int*   p2f    = (const int*)  d_in[1];
    const float* bary   = (const float*)d_in[2];
    const float* dists  = (const float*)d_in[3];
    const float* fmem   = (const float*)d_in[4];
    const int*   pfaces = (const int*)  d_in[5];
    // d_in[6] = num_verts (device scalar; V derived from out_size instead)
    const int*   mdp    = (const int*)  d_in[7];

    const long long P  = in_sizes[0];        // N*H*W*K = 2097152
    const int HW  = (int)(P / N_MESH);       // 262144 pixels
    const int F3  = in_sizes[5];             // F*3
    const int C   = in_sizes[4] / F3;        // 32
    const int V   = (int)((long long)out_size - P * C - 7 * P);  // 10002

    float* out     = (float*)d_out;
    float* out_map = out;                    // P*C
    float* vv      = out_map + P * C;        // V
    float* maskO   = vv + V;                 // P
    float* zbO     = maskO + P;              // P
    float* pO      = zbO + P;                // P
    float* dO      = pO + P;                 // P
    float* bcO     = dO + P;                 // 3P

    zero_vv<<<dim3((V + 255) / 256), dim3(256), 0, stream>>>(vv, V);

    raster_fused<<<dim3(HW / 256, N_MESH), dim3(256), 0, stream>>>(
        zbuf, p2f, bary, dists, fmem, pfaces, mdp,
        out_map, maskO, zbO, pO, dO, bcO,
        vv, HW, C);
}